// Round 7
// baseline (188.734 us; speedup 1.0000x reference)
//
#include <hip/hip_runtime.h>

typedef unsigned short u16;
typedef u16 u16x8 __attribute__((ext_vector_type(8)));
typedef __bf16 bf16x8 __attribute__((ext_vector_type(8)));
typedef float f32x4 __attribute__((ext_vector_type(4)));

#define T_SEQ 2048
#define DIM 1024
#define NH 16
#define HD 64

#define MFMA(a, b, c) __builtin_amdgcn_mfma_f32_16x16x32_bf16(a, b, c, 0, 0, 0)

// native f32->bf16 (RTNE)
__device__ __forceinline__ u16 f2bf(float f) {
  return __builtin_bit_cast(u16, static_cast<__bf16>(f));
}

__device__ __forceinline__ bf16x8 ld8(const u16* p) {
  return __builtin_bit_cast(bf16x8, *(const u16x8*)p);
}

// async global->LDS DMA, 16B per lane; LDS dest = wave-uniform base + lane*16.
__device__ __forceinline__ void gload_lds16(const u16* g, u16* l) {
  __builtin_amdgcn_global_load_lds((const __attribute__((address_space(1))) void*)(g),
                                   (__attribute__((address_space(3))) void*)(l),
                                   16, 0, 0);
}

// ---------------- fused prep: x conv + both weight transposes ----------------
__global__ void k_prep(const float* __restrict__ X, u16* __restrict__ Y,
                       const float* __restrict__ Wq, u16* __restrict__ WqT,
                       const float* __restrict__ Wp, u16* __restrict__ WpT) {
  __shared__ float tile[32][33];
  int bid = blockIdx.x;
  if (bid < 4096) {  // convert x: 4 elems/thread
    int i = (bid * 256 + threadIdx.x) * 4;
    float4 f = *(const float4*)&X[i];
    ushort4 o = make_ushort4(f2bf(f.x), f2bf(f.y), f2bf(f.z), f2bf(f.w));
    *(ushort4*)&Y[i] = o;
    return;
  }
  const float* W; u16* WT; int K = 1024, N, bx, by;
  if (bid < 4096 + 3072) { int t = bid - 4096; W = Wq; WT = WqT; N = 3072; bx = t % 96; by = t / 96; }
  else                   { int t = bid - 7168; W = Wp; WT = WpT; N = 1024; bx = t % 32; by = t / 32; }
  int tx = threadIdx.x & 31, ty = threadIdx.x >> 5;  // ty 0..7
  int c0 = bx * 32, r0 = by * 32;
#pragma unroll
  for (int r = 0; r < 4; r++)
    tile[ty + r * 8][tx] = W[(r0 + ty + r * 8) * N + c0 + tx];
  __syncthreads();
#pragma unroll
  for (int r = 0; r < 4; r++)
    WT[(c0 + ty + r * 8) * K + r0 + tx] = f2bf(tile[tx][ty + r * 8]);
}

// ------- GEMM core v2: 3-buffer ring, counted vmcnt, raw s_barrier (T3/T4) -------
// K=1024 fixed -> 32 BK=32 steps. Prologue stages buf0(k=0), buf1(k=32).
// Step s: wait vmcnt(4) [stage(s) complete, stage(s+1) stays IN FLIGHT across
// the barrier - never drain to 0 mid-loop], s_barrier, issue stage(s+2) into
// buf((s+2)%3) [= buf((s-1)%3), readers all passed this barrier], compute
// buf(s%3). Last step waits vmcnt(0). Measured R6: total 216.9->188.2us.

#define GEMM_STAGE3(buf, kk)                                                      \
  {                                                                               \
    _Pragma("unroll") for (int p = 0; p < 2; p++) {                               \
      int rr = w * 32 + p * 16;                                                   \
      gload_lds16(&Agp[(size_t)(rowBase + rr + srow) * Kd + (kk) + schunk],       \
                  &As[buf][rr * 32]);                                             \
      gload_lds16(&Bgp[(size_t)(colBase + rr + srow) * Kd + (kk) + schunk],       \
                  &Bs[buf][rr * 32]);                                             \
    }                                                                             \
  }

#define GEMM_COMPUTE3(buf)                                                        \
  {                                                                               \
    bf16x8 af[4], bfv[4];                                                         \
    _Pragma("unroll") for (int i = 0; i < 4; i++) {                               \
      af[i] = ld8(&As[buf][(wm * 64 + i * 16 + l15) * 32 + quad * 8]);            \
      bfv[i] = ld8(&Bs[buf][(wn * 64 + i * 16 + l15) * 32 + quad * 8]);           \
    }                                                                             \
    _Pragma("unroll") for (int i = 0; i < 4; i++)                                 \
        _Pragma("unroll") for (int j = 0; j < 4; j++)                             \
            acc[i][j] = MFMA(af[i], bfv[j], acc[i][j]);                           \
  }

#define GEMM_CORE3(Aptr, BTptr, bxv, byv)                                         \
  const int tid = threadIdx.x;                                                    \
  const int lane = tid & 63, w = tid >> 6;                                        \
  const int l15 = lane & 15, quad = lane >> 4;                                    \
  const int wm = w >> 1, wn = w & 1;                                              \
  const int rowBase = (byv) * 128;                                                \
  const int colBase = (bxv) * 128;                                                \
  const u16* Agp = (Aptr);                                                        \
  const u16* Bgp = (BTptr);                                                       \
  const int Kd = DIM;                                                             \
  f32x4 acc[4][4];                                                                \
  _Pragma("unroll") for (int i = 0; i < 4; i++)                                   \
      _Pragma("unroll") for (int j = 0; j < 4; j++)                               \
          acc[i][j] = (f32x4){0.f, 0.f, 0.f, 0.f};                                \
  const int srow = lane >> 2;        /* 0..15: row within 16-row group */         \
  const int schunk = (lane & 3) * 8; /* elem offset of this lane's 16B chunk */   \
  GEMM_STAGE3(0, 0)                                                               \
  GEMM_STAGE3(1, 32)                                                              \
  _Pragma("unroll") for (int s = 0; s < 32; ++s) {                                \
    if (s < 31) { asm volatile("s_waitcnt vmcnt(4)" ::: "memory"); }              \
    else        { asm volatile("s_waitcnt vmcnt(0)" ::: "memory"); }              \
    __builtin_amdgcn_s_barrier();                                                 \
    if (s + 2 < 32) { GEMM_STAGE3((s + 2) % 3, (s + 2) * 32) }                    \
    GEMM_COMPUTE3(s % 3)                                                          \
  }                                                                               \
  __syncthreads(); /* all reads done before any epilogue LDS overwrite */

// ---------------- GEMM1: x @ qkv_w + b, fused RoPE, scatter q/k/vT ----------------
// LDS-staged coalesced epilogue (R2): WRITE_SIZE 50MB->25MB.
#define EPLD 136

__global__ __launch_bounds__(256) void k_gemm_qkv(
    const u16* __restrict__ A, const u16* __restrict__ BT,
    const float* __restrict__ bias,
    const float* __restrict__ rsin, const float* __restrict__ rcos,
    u16* __restrict__ qb, u16* __restrict__ kb, u16* __restrict__ vtb) {
  __shared__ __align__(16) u16 LDSBUF[24576];        // 48 KB: 3x(A 4096 + B 4096) u16
  u16 (*As)[128 * 32] = (u16(*)[128 * 32])(LDSBUF);
  u16 (*Bs)[128 * 32] = (u16(*)[128 * 32])(LDSBUF + 12288);
  const int n = blockIdx.x, xcd = n & 7, s = n >> 3;
  const int cg = xcd & 1, rg = xcd >> 1;
  const int bxv = cg * 12 + (s >> 3);   // 0..23
  const int byv = rg * 8 + (s & 7);     // 0..31
  GEMM_CORE3(A, BT, bxv, byv)

#pragma unroll
  for (int j = 0; j < 4; j++) {
    float bv = bias[colBase + wn * 64 + j * 16 + l15];
#pragma unroll
    for (int i = 0; i < 4; i++)
#pragma unroll
      for (int r = 0; r < 4; r++) acc[i][j][r] += bv;
  }

  const int colW = colBase + wn * 64;
  const int sec = colW >> 10;            // 0=Q 1=K 2=V (block-uniform)

  if (sec == 2) {
#pragma unroll
    for (int i = 0; i < 4; i++)
#pragma unroll
      for (int r = 0; r < 4; r++) {
        int tl = wm * 64 + i * 16 + quad * 4 + r;
#pragma unroll
        for (int j = 0; j < 4; j++) {
          int d2 = wn * 64 + j * 16 + l15;
          LDSBUF[d2 * EPLD + tl] = f2bf(acc[i][j][r]);   // transposed: [d2][t]
        }
      }
  } else {
#pragma unroll
    for (int i = 0; i < 4; i++)
#pragma unroll
      for (int r = 0; r < 4; r++) {
        int tl = wm * 64 + i * 16 + quad * 4 + r;
        int t = (rowBase + tl) & 2047;
#pragma unroll
        for (int j = 0; j < 4; j++) {
          int d = j * 16 + l15;            // 0..63 within head
          float v = acc[i][j][r];
          float pr = acc[i][j ^ 2][r];
          float rot = (j < 2) ? -pr : pr;
          float rv = v * rcos[t * HD + d] + rot * rsin[t * HD + d];
          if (sec == 0) rv *= 0.125f;      // fold 1/sqrt(64) into Q
          LDSBUF[tl * EPLD + wn * 64 + d] = f2bf(rv);
        }
      }
  }
  __syncthreads();

  const int hb = (colBase & 1023) >> 6;    // first head of tile within section
  const int b = rowBase >> 11, t0 = rowBase & 2047;
  if (sec == 2) {
#pragma unroll
    for (int p = 0; p < 8; p++) {
      int drow = (tid >> 4) + p * 16;      // local d2 0..127
      int tc = (tid & 15) * 8;             // local t chunk
      int hh = hb + (drow >> 6), d = drow & 63;
      u16x8 v = *(const u16x8*)&LDSBUF[drow * EPLD + tc];
      *(u16x8*)&vtb[((size_t)(b * NH + hh) * HD + d) * T_SEQ + t0 + tc] = v;
    }
  } else {
    u16* dst = (sec == 0) ? qb : kb;
#pragma unroll
    for (int p = 0; p < 8; p++) {
      int row = (tid >> 4) + p * 16;       // local t 0..127
      int dc = (tid & 15) * 8;             // local col chunk 0..120
      int hh = hb + (dc >> 6), d = dc & 63;
      u16x8 v = *(const u16x8*)&LDSBUF[row * EPLD + dc];
      *(u16x8*)&dst[((size_t)(b * NH + hh) * T_SEQ + t0 + row) * HD + d] = v;
    }
  }
}

// ---------------- GEMM2: y @ proj_w + proj_b -> fp32 out ----------------
__global__ __launch_bounds__(256) void k_gemm_proj(
    const u16* __restrict__ A, const u16* __restrict__ BT,
    const float* __restrict__ bias, float* __restrict__ C) {
  __shared__ __align__(16) u16 LDSBUF[24576];        // 48 KB: 3x(A + B)
  u16 (*As)[128 * 32] = (u16(*)[128 * 32])(LDSBUF);
  u16 (*Bs)[128 * 32] = (u16(*)[128 * 32])(LDSBUF + 12288);
  const int n = blockIdx.x, xcd = n & 7, s = n >> 3;
  const int cg = xcd & 1, rg = xcd >> 1;
  const int bxv = cg * 4 + (s >> 3);    // 0..7
  const int byv = rg * 8 + (s & 7);     // 0..31
  GEMM_CORE3(A, BT, bxv, byv)

#pragma unroll
  for (int i = 0; i < 4; i++)
#pragma unroll
    for (int r = 0; r < 4; r++) {
      int grow = rowBase + wm * 64 + i * 16 + quad * 4 + r;
#pragma unroll
      for (int j = 0; j < 4; j++) {
        int col = colBase + wn * 64 + j * 16 + l15;
        C[grow * DIM + col] = acc[i][j][r] + bias[col];
      }
    }
}

// ---------------- Flash attention v4: 128 q-rows/block, 8 waves (R7) ----------------
// R6 counters (attn 48us): MfmaUtil 14 / VALU 34 / HBM 5.5 / Occ 25 -> >50% idle,
// 3 blocks/CU TLP can't cover the serial chunk chain, and every 64-row block
// re-staged K/V at 2x the compulsory rate. This version: 512 threads, 8 waves,
// 128 q-rows/block. Same per-wave code as R3 (measured 48.1us). Per-CU wave-chunk
// work identical; K/V staging traffic HALVES; LDS 70,656B -> 2 blocks/CU =
// 16 waves/CU (50% cap vs 37.5%). Grid 32x16 = exactly 2/CU, heavy-first.
#define KLD 72
#define VLD 136

__global__ __launch_bounds__(512, 2) void k_attn(
    const u16* __restrict__ qb, const u16* __restrict__ kb,
    const u16* __restrict__ vtb, u16* __restrict__ yb) {
  __shared__ __align__(16) u16 Ks[128 * KLD];        // 18,432 B (128 keys x 64 hd)
  __shared__ __align__(16) u16 VTs[64 * VLD];        // 17,408 B (64 d x 128 t)
  __shared__ __align__(16) u16 Ps[8 * 16 * VLD];     // 34,816 B (8 waves x 16 P rows; Q+O staged here)
  const int tid = threadIdx.x;
  const int lane = tid & 63, w = tid >> 6;           // w 0..7
  const int l15 = lane & 15, quad = lane >> 4;
  const int bh = blockIdx.x;
  const int qp = 15 - blockIdx.y;                    // 128-row q tile; heaviest first

  const u16* qp_ = qb + (size_t)bh * T_SEQ * HD;
  const u16* kp = kb + (size_t)bh * T_SEQ * HD;
  const u16* vp = vtb + (size_t)bh * HD * T_SEQ;

  const int nch = qp + 1;                            // 128-key chunks
  const int qrow_base = qp * 128 + w * 16 + quad * 4;

  // staging maps (512 threads)
  const int kr = tid >> 3, kc = (tid & 7) * 8;       // K/Q: rows tid>>3 + p*64, 8 col-chunks
  const int vr = tid >> 4, vc = (tid & 15) * 8;      // V: d rows tid>>4 + p*32, 16 t-chunks

  u16x8 kreg[2], vreg[2];
#define LOADKV(c)                                                              \
  {                                                                            \
    _Pragma("unroll") for (int p = 0; p < 2; p++)                              \
        kreg[p] = *(const u16x8*)&kp[((c) * 128 + kr + p * 64) * HD + kc];     \
    _Pragma("unroll") for (int p = 0; p < 2; p++)                              \
        vreg[p] = *(const u16x8*)&vp[(vr + p * 32) * T_SEQ + (c) * 128 + vc];  \
  }
#define WRITEKV()                                                              \
  {                                                                            \
    _Pragma("unroll") for (int p = 0; p < 2; p++)                              \
        *(u16x8*)&Ks[(kr + p * 64) * KLD + kc] = kreg[p];                      \
    _Pragma("unroll") for (int p = 0; p < 2; p++)                              \
        *(u16x8*)&VTs[(vr + p * 32) * VLD + vc] = vreg[p];                     \
  }

  LOADKV(0)  // chunk 0 in flight while Q stages

  {  // stage Q (128 rows) into Ps region, KLD stride
#pragma unroll
    for (int p = 0; p < 2; p++) {
      int r = kr + p * 64;
      *(u16x8*)&Ps[r * KLD + kc] = *(const u16x8*)&qp_[(qp * 128 + r) * HD + kc];
    }
  }
  __syncthreads();
  bf16x8 qa0 = ld8(&Ps[(w * 16 + l15) * KLD + quad * 8]);
  bf16x8 qa1 = ld8(&Ps[(w * 16 + l15) * KLD + 32 + quad * 8]);
  WRITEKV()       // chunk 0 -> Ks/VTs (disjoint from Ps; qa reads protected by barrier)
  __syncthreads();

  f32x4 o[4];
#pragma unroll
  for (int j = 0; j < 4; j++) o[j] = (f32x4){0.f, 0.f, 0.f, 0.f};
  float li[4] = {0.f, 0.f, 0.f, 0.f};

  u16* ps = &Ps[w * 16 * VLD];  // this wave's 16 P rows
  // sigma read row for PV A-fragment (lane wants logical P row l15)
  const int srd = ((l15 & 1) << 3) | ((l15 >> 2) << 1) | ((l15 >> 1) & 1);

  for (int c = 0; c < nch; c++) {
    if (c + 1 < nch) LOADKV(c + 1)  // hide global latency under compute

    // S = Q K^T : 16 q rows x 128 keys per wave
    f32x4 s[8];
#pragma unroll
    for (int j = 0; j < 8; j++) {
      s[j] = (f32x4){0.f, 0.f, 0.f, 0.f};
      bf16x8 b0 = ld8(&Ks[(j * 16 + l15) * KLD + quad * 8]);
      bf16x8 b1 = ld8(&Ks[(j * 16 + l15) * KLD + 32 + quad * 8]);
      s[j] = MFMA(qa0, b0, s[j]);
      s[j] = MFMA(qa1, b1, s[j]);
    }

    // exp (no max shift), causal zeroing on the last chunk only, per-lane li
    const bool lastc = (c == nch - 1);
#pragma unroll
    for (int r = 0; r < 4; r++) {
      const int swr = ((r & 1) << 3) | (quad << 1) | (r >> 1);  // sigma write row
#pragma unroll
      for (int j = 0; j < 8; j++) {
        float e = __expf(s[j][r]);
        if (lastc && (c * 128 + j * 16 + l15 > qrow_base + r)) e = 0.f;
        li[r] += e;
        ps[swr * VLD + j * 16 + l15] = f2bf(e);
      }
    }

    // PV: P(16x128) @ V(128x64); P read back in A-layout (wave-private, sigma rows)
#pragma unroll
    for (int c4 = 0; c4 < 4; c4++) {
      bf16x8 pa = ld8(&ps[srd * VLD + c4 * 32 + quad * 8]);
#pragma unroll
      for (int j2 = 0; j2 < 4; j2++) {
        bf16x8 vb = ld8(&VTs[(j2 * 16 + l15) * VLD + c4 * 32 + quad * 8]);
        o[j2] = MFMA(pa, vb, o[j2]);
      }
    }
    __syncthreads();             // all waves done reading Ks/VTs
    if (c + 1 < nch) {
      WRITEKV()                  // next chunk -> LDS (vmcnt drained by compiler)
      __syncthreads();           // LDS ready for next iteration
    }
  }

  // one-time li reduction across the 16-lane column group
#pragma unroll
  for (int r = 0; r < 4; r++) {
#pragma unroll
    for (int off = 8; off >= 1; off >>= 1) li[r] += __shfl_xor(li[r], off, 16);
    li[r] = 1.0f / li[r];
  }

  // stage O in Ps (sigma rows) then coalesced u16x8 stores
#pragma unroll
  for (int j = 0; j < 4; j++)
#pragma unroll
    for (int r = 0; r < 4; r++) {
      const int swr = ((r & 1) << 3) | (quad << 1) | (r >> 1);
      ps[swr * VLD + j * 16 + l15] = f2bf(o[j][r] * li[r]);
    }
  __syncthreads();

  const int b = bh >> 4, h = bh & 15;
#pragma unroll
  for (int p = 0; p < 2; p++) {
    int row = kr + p * 64;               // logical O row 0..127
    int m = row & 15;
    int srow = ((m & 1) << 3) | ((m >> 2) << 1) | ((m >> 1) & 1);
    int t = qp * 128 + row;
    *(u16x8*)&yb[((size_t)(b * T_SEQ + t) * NH + h) * HD + kc] =
        *(const u16x8*)&Ps[(((row >> 4) << 4) | srow) * VLD + kc];
  }
}

// ---------------- launch ----------------
extern "C" void kernel_launch(void* const* d_in, const int* in_sizes, int n_in,
                              void* d_out, int out_size, void* d_ws, size_t ws_size,
                              hipStream_t stream) {
  const float* x      = (const float*)d_in[0];
  // d_in[1] = mask (causal tril) — recomputed analytically, not read
  const float* rsin   = (const float*)d_in[2];
  const float* rcos   = (const float*)d_in[3];
  const float* qkv_w  = (const float*)d_in[4];
  const float* qkv_b  = (const float*)d_in[5];
  const float* proj_w = (const float*)d_in[6];
  const float* proj_b = (const float*)d_in[7];
  float* out = (float*)d_out;

  char* ws = (char*)d_ws;
  u16* x_bf  = (u16*)(ws);                    // 4096*1024      = 8 MB
  u16* qkvT  = (u16*)(ws + (8ull << 20));     // 3072*1024      = 6 MB
  u16* projT = (u16*)(ws + (14ull << 20));    // 1024*1024      = 2 MB
  u16* q_buf = (u16*)(ws + (16ull << 20));    // [b,h,t,d]      = 8 MB
  u16* k_buf = (u16*)(ws + (24ull << 20));    // [b,h,t,d]      = 8 MB
  u16* vT    = (u16*)(ws + (32ull << 20));    // [b,h,d,t]      = 8 MB
  u16* y_buf = (u16*)(ws + (40ull << 20));    // [b,t,h,d]      = 8 MB

  hipLaunchKernelGGL(k_prep, dim3(8192), dim3(256), 0, stream,
                     x, x_bf, qkv_w, qkvT, proj_w, projT);
  hipLaunchKernelGGL(k_gemm_qkv, dim3(768), dim3(256), 0, stream,
                     x_bf, qkvT, qkv_b, rsin, rcos, q_buf, k_buf, vT);
  hipLaunchKernelGGL(k_attn, dim3(32, 16), dim3(512), 0, stream,
                     q_buf, k_buf, vT, y_buf);
  hipLaunchKernelGGL(k_gemm_proj, dim3(256), dim3(256), 0, stream,
                     y_buf, projT, proj_b, out);
}

// Round 8
// 183.344 us; speedup vs baseline: 1.0294x; 1.0294x over previous
//
#include <hip/hip_runtime.h>

typedef unsigned short u16;
typedef u16 u16x8 __attribute__((ext_vector_type(8)));
typedef __bf16 bf16x8 __attribute__((ext_vector_type(8)));
typedef float f32x4 __attribute__((ext_vector_type(4)));

#define T_SEQ 2048
#define DIM 1024
#define NH 16
#define HD 64

#define MFMA(a, b, c) __builtin_amdgcn_mfma_f32_16x16x32_bf16(a, b, c, 0, 0, 0)

// native f32->bf16 (RTNE)
__device__ __forceinline__ u16 f2bf(float f) {
  return __builtin_bit_cast(u16, static_cast<__bf16>(f));
}

__device__ __forceinline__ bf16x8 ld8(const u16* p) {
  return __builtin_bit_cast(bf16x8, *(const u16x8*)p);
}

// async global->LDS DMA, 16B per lane; LDS dest = wave-uniform base + lane*16.
__device__ __forceinline__ void gload_lds16(const u16* g, u16* l) {
  __builtin_amdgcn_global_load_lds((const __attribute__((address_space(1))) void*)(g),
                                   (__attribute__((address_space(3))) void*)(l),
                                   16, 0, 0);
}

// ---------------- fused prep: x conv + both weight transposes ----------------
__global__ void k_prep(const float* __restrict__ X, u16* __restrict__ Y,
                       const float* __restrict__ Wq, u16* __restrict__ WqT,
                       const float* __restrict__ Wp, u16* __restrict__ WpT) {
  __shared__ float tile[32][33];
  int bid = blockIdx.x;
  if (bid < 4096) {  // convert x: 4 elems/thread
    int i = (bid * 256 + threadIdx.x) * 4;
    float4 f = *(const float4*)&X[i];
    ushort4 o = make_ushort4(f2bf(f.x), f2bf(f.y), f2bf(f.z), f2bf(f.w));
    *(ushort4*)&Y[i] = o;
    return;
  }
  const float* W; u16* WT; int K = 1024, N, bx, by;
  if (bid < 4096 + 3072) { int t = bid - 4096; W = Wq; WT = WqT; N = 3072; bx = t % 96; by = t / 96; }
  else                   { int t = bid - 7168; W = Wp; WT = WpT; N = 1024; bx = t % 32; by = t / 32; }
  int tx = threadIdx.x & 31, ty = threadIdx.x >> 5;  // ty 0..7
  int c0 = bx * 32, r0 = by * 32;
#pragma unroll
  for (int r = 0; r < 4; r++)
    tile[ty + r * 8][tx] = W[(r0 + ty + r * 8) * N + c0 + tx];
  __syncthreads();
#pragma unroll
  for (int r = 0; r < 4; r++)
    WT[(c0 + ty + r * 8) * K + r0 + tx] = f2bf(tile[tx][ty + r * 8]);
}

// ------- GEMM core v2: 3-buffer ring, counted vmcnt, raw s_barrier (T3/T4) -------
// Measured R6: total 216.9->188.2us. FROZEN.

#define GEMM_STAGE3(buf, kk)                                                      \
  {                                                                               \
    _Pragma("unroll") for (int p = 0; p < 2; p++) {                               \
      int rr = w * 32 + p * 16;                                                   \
      gload_lds16(&Agp[(size_t)(rowBase + rr + srow) * Kd + (kk) + schunk],       \
                  &As[buf][rr * 32]);                                             \
      gload_lds16(&Bgp[(size_t)(colBase + rr + srow) * Kd + (kk) + schunk],       \
                  &Bs[buf][rr * 32]);                                             \
    }                                                                             \
  }

#define GEMM_COMPUTE3(buf)                                                        \
  {                                                                               \
    bf16x8 af[4], bfv[4];                                                         \
    _Pragma("unroll") for (int i = 0; i < 4; i++) {                               \
      af[i] = ld8(&As[buf][(wm * 64 + i * 16 + l15) * 32 + quad * 8]);            \
      bfv[i] = ld8(&Bs[buf][(wn * 64 + i * 16 + l15) * 32 + quad * 8]);           \
    }                                                                             \
    _Pragma("unroll") for (int i = 0; i < 4; i++)                                 \
        _Pragma("unroll") for (int j = 0; j < 4; j++)                             \
            acc[i][j] = MFMA(af[i], bfv[j], acc[i][j]);                           \
  }

#define GEMM_CORE3(Aptr, BTptr, bxv, byv)                                         \
  const int tid = threadIdx.x;                                                    \
  const int lane = tid & 63, w = tid >> 6;                                        \
  const int l15 = lane & 15, quad = lane >> 4;                                    \
  const int wm = w >> 1, wn = w & 1;                                              \
  const int rowBase = (byv) * 128;                                                \
  const int colBase = (bxv) * 128;                                                \
  const u16* Agp = (Aptr);                                                        \
  const u16* Bgp = (BTptr);                                                       \
  const int Kd = DIM;                                                             \
  f32x4 acc[4][4];                                                                \
  _Pragma("unroll") for (int i = 0; i < 4; i++)                                   \
      _Pragma("unroll") for (int j = 0; j < 4; j++)                               \
          acc[i][j] = (f32x4){0.f, 0.f, 0.f, 0.f};                                \
  const int srow = lane >> 2;        /* 0..15: row within 16-row group */         \
  const int schunk = (lane & 3) * 8; /* elem offset of this lane's 16B chunk */   \
  GEMM_STAGE3(0, 0)                                                               \
  GEMM_STAGE3(1, 32)                                                              \
  _Pragma("unroll") for (int s = 0; s < 32; ++s) {                                \
    if (s < 31) { asm volatile("s_waitcnt vmcnt(4)" ::: "memory"); }              \
    else        { asm volatile("s_waitcnt vmcnt(0)" ::: "memory"); }              \
    __builtin_amdgcn_s_barrier();                                                 \
    if (s + 2 < 32) { GEMM_STAGE3((s + 2) % 3, (s + 2) * 32) }                    \
    GEMM_COMPUTE3(s % 3)                                                          \
  }                                                                               \
  __syncthreads(); /* all reads done before any epilogue LDS overwrite */

// ---------------- GEMM1: x @ qkv_w + b, fused RoPE, scatter q/k/vT ----------------
#define EPLD 136

__global__ __launch_bounds__(256) void k_gemm_qkv(
    const u16* __restrict__ A, const u16* __restrict__ BT,
    const float* __restrict__ bias,
    const float* __restrict__ rsin, const float* __restrict__ rcos,
    u16* __restrict__ qb, u16* __restrict__ kb, u16* __restrict__ vtb) {
  __shared__ __align__(16) u16 LDSBUF[24576];        // 48 KB: 3x(A 4096 + B 4096) u16
  u16 (*As)[128 * 32] = (u16(*)[128 * 32])(LDSBUF);
  u16 (*Bs)[128 * 32] = (u16(*)[128 * 32])(LDSBUF + 12288);
  const int n = blockIdx.x, xcd = n & 7, s = n >> 3;
  const int cg = xcd & 1, rg = xcd >> 1;
  const int bxv = cg * 12 + (s >> 3);   // 0..23
  const int byv = rg * 8 + (s & 7);     // 0..31
  GEMM_CORE3(A, BT, bxv, byv)

#pragma unroll
  for (int j = 0; j < 4; j++) {
    float bv = bias[colBase + wn * 64 + j * 16 + l15];
#pragma unroll
    for (int i = 0; i < 4; i++)
#pragma unroll
      for (int r = 0; r < 4; r++) acc[i][j][r] += bv;
  }

  const int colW = colBase + wn * 64;
  const int sec = colW >> 10;            // 0=Q 1=K 2=V (block-uniform)

  if (sec == 2) {
#pragma unroll
    for (int i = 0; i < 4; i++)
#pragma unroll
      for (int r = 0; r < 4; r++) {
        int tl = wm * 64 + i * 16 + quad * 4 + r;
#pragma unroll
        for (int j = 0; j < 4; j++) {
          int d2 = wn * 64 + j * 16 + l15;
          LDSBUF[d2 * EPLD + tl] = f2bf(acc[i][j][r]);   // transposed: [d2][t]
        }
      }
  } else {
#pragma unroll
    for (int i = 0; i < 4; i++)
#pragma unroll
      for (int r = 0; r < 4; r++) {
        int tl = wm * 64 + i * 16 + quad * 4 + r;
        int t = (rowBase + tl) & 2047;
#pragma unroll
        for (int j = 0; j < 4; j++) {
          int d = j * 16 + l15;            // 0..63 within head
          float v = acc[i][j][r];
          float pr = acc[i][j ^ 2][r];
          float rot = (j < 2) ? -pr : pr;
          float rv = v * rcos[t * HD + d] + rot * rsin[t * HD + d];
          if (sec == 0) rv *= 0.125f;      // fold 1/sqrt(64) into Q
          LDSBUF[tl * EPLD + wn * 64 + d] = f2bf(rv);
        }
      }
  }
  __syncthreads();

  const int hb = (colBase & 1023) >> 6;    // first head of tile within section
  const int b = rowBase >> 11, t0 = rowBase & 2047;
  if (sec == 2) {
#pragma unroll
    for (int p = 0; p < 8; p++) {
      int drow = (tid >> 4) + p * 16;      // local d2 0..127
      int tc = (tid & 15) * 8;             // local t chunk
      int hh = hb + (drow >> 6), d = drow & 63;
      u16x8 v = *(const u16x8*)&LDSBUF[drow * EPLD + tc];
      *(u16x8*)&vtb[((size_t)(b * NH + hh) * HD + d) * T_SEQ + t0 + tc] = v;
    }
  } else {
    u16* dst = (sec == 0) ? qb : kb;
#pragma unroll
    for (int p = 0; p < 8; p++) {
      int row = (tid >> 4) + p * 16;       // local t 0..127
      int dc = (tid & 15) * 8;             // local col chunk 0..120
      int hh = hb + (dc >> 6), d = dc & 63;
      u16x8 v = *(const u16x8*)&LDSBUF[row * EPLD + dc];
      *(u16x8*)&dst[((size_t)(b * NH + hh) * T_SEQ + t0 + row) * HD + d] = v;
    }
  }
}

// ---------------- GEMM2: y @ proj_w + proj_b -> fp32 out ----------------
__global__ __launch_bounds__(256) void k_gemm_proj(
    const u16* __restrict__ A, const u16* __restrict__ BT,
    const float* __restrict__ bias, float* __restrict__ C) {
  __shared__ __align__(16) u16 LDSBUF[24576];        // 48 KB: 3x(A + B)
  u16 (*As)[128 * 32] = (u16(*)[128 * 32])(LDSBUF);
  u16 (*Bs)[128 * 32] = (u16(*)[128 * 32])(LDSBUF + 12288);
  const int n = blockIdx.x, xcd = n & 7, s = n >> 3;
  const int cg = xcd & 1, rg = xcd >> 1;
  const int bxv = cg * 4 + (s >> 3);    // 0..7
  const int byv = rg * 8 + (s & 7);     // 0..31
  GEMM_CORE3(A, BT, bxv, byv)

#pragma unroll
  for (int i = 0; i < 4; i++)
#pragma unroll
    for (int r = 0; r < 4; r++) {
      int grow = rowBase + wm * 64 + i * 16 + quad * 4 + r;
#pragma unroll
      for (int j = 0; j < 4; j++) {
        int col = colBase + wn * 64 + j * 16 + l15;
        C[grow * DIM + col] = acc[i][j][r] + bias[col];
      }
    }
}

// ---------------- Flash attention v5: 64 q-rows, 4 waves, split-write barriers ----------------
// R8. R7 (8-wave/128-row) regressed: occupancy stayed 25%, fetch unchanged -> revert
// to the proven R3 64-row body. New: the R3 chain had sync;WRITEKV;sync with the
// write block dead on the critical path. Split it:
//   QK -> [lgkm0+s_barrier] -> WRITEK(c+1)   (drains under softmax+PV, no Ks readers)
//   PV -> [__syncthreads]   -> WRITEV(c+1)   (drains under next QK, no VTs readers)
// Visibility: K-writes published by bar2 (syncthreads lgkm drain) before next QK;
// V-writes drained at next iter's bar1 lgkmcnt(0) before any wave's PV. Last chunk
// skips both (no re-stage) -> one barrier fewer.
#define KLD 72
#define VLD 136

__global__ __launch_bounds__(256, 3) void k_attn(
    const u16* __restrict__ qb, const u16* __restrict__ kb,
    const u16* __restrict__ vtb, u16* __restrict__ yb) {
  __shared__ __align__(16) u16 Ks[128 * KLD];       // 18.4 KB  (128 keys x 64 hd)
  __shared__ __align__(16) u16 VTs[64 * VLD];       // 17.4 KB  (64 d x 128 t)
  __shared__ __align__(16) u16 Ps[64 * VLD];        // 17.4 KB  P staging; Q staged here at start
  const int tid = threadIdx.x;
  const int lane = tid & 63, w = tid >> 6;
  const int l15 = lane & 15, quad = lane >> 4;
  const int bh = blockIdx.x;
  const int qt = 31 - blockIdx.y;     // heaviest blocks dispatch first

  const u16* qp = qb + (size_t)bh * T_SEQ * HD;
  const u16* kp = kb + (size_t)bh * T_SEQ * HD;
  const u16* vp = vtb + (size_t)bh * HD * T_SEQ;

  const int nch = (qt + 2) >> 1;  // ceil((qt+1)/2) 128-key chunks
  const int qrow_base = qt * 64 + w * 16 + quad * 4;

  // staging thread->addr map (constant across chunks)
  const int sr = tid >> 3, sc = (tid & 7) * 8;      // K: 32 rows x 8 chunks
  const int vr = tid >> 4, vc = (tid & 15) * 8;     // V: 16 rows x 16 chunks

  u16x8 kreg[4], vreg[4];
#define LOADKV(c)                                                              \
  {                                                                            \
    _Pragma("unroll") for (int p = 0; p < 4; p++)                              \
        kreg[p] = *(const u16x8*)&kp[((c) * 128 + sr + p * 32) * HD + sc];     \
    _Pragma("unroll") for (int p = 0; p < 4; p++)                              \
        vreg[p] = *(const u16x8*)&vp[(vr + p * 16) * T_SEQ + (c) * 128 + vc];  \
  }
#define WRITEK()                                                               \
  {                                                                            \
    _Pragma("unroll") for (int p = 0; p < 4; p++)                              \
        *(u16x8*)&Ks[(sr + p * 32) * KLD + sc] = kreg[p];                      \
  }
#define WRITEV()                                                               \
  {                                                                            \
    _Pragma("unroll") for (int p = 0; p < 4; p++)                              \
        *(u16x8*)&VTs[(vr + p * 16) * VLD + vc] = vreg[p];                     \
  }

  LOADKV(0)  // chunk 0 in flight while Q stages

  {  // stage Q once (into Ps region, KLD stride)
#pragma unroll
    for (int p = 0; p < 2; p++) {
      int r = sr + p * 32;
      *(u16x8*)&Ps[r * KLD + sc] = *(const u16x8*)&qp[(qt * 64 + r) * HD + sc];
    }
  }
  __syncthreads();
  bf16x8 qa0 = ld8(&Ps[(w * 16 + l15) * KLD + quad * 8]);
  bf16x8 qa1 = ld8(&Ps[(w * 16 + l15) * KLD + 32 + quad * 8]);
  WRITEK()        // chunk 0 K -> LDS (vmcnt by compiler; qa reads drained at barrier)
  WRITEV()        // chunk 0 V -> LDS
  __syncthreads();

  f32x4 o[4];
#pragma unroll
  for (int j = 0; j < 4; j++) o[j] = (f32x4){0.f, 0.f, 0.f, 0.f};
  float li[4] = {0.f, 0.f, 0.f, 0.f};

  u16* ps = &Ps[w * 16 * VLD];  // this wave's 16 P rows
  // sigma read row for PV A-fragment (lane wants logical P row l15)
  const int srd = ((l15 & 1) << 3) | ((l15 >> 2) << 1) | ((l15 >> 1) & 1);

  for (int c = 0; c < nch; c++) {
    const bool more = (c + 1 < nch);
    if (more) LOADKV(c + 1)  // global loads in flight under this chunk's compute

    // S = Q K^T : 16 q rows x 128 keys per wave
    f32x4 s[8];
#pragma unroll
    for (int j = 0; j < 8; j++) {
      s[j] = (f32x4){0.f, 0.f, 0.f, 0.f};
      bf16x8 b0 = ld8(&Ks[(j * 16 + l15) * KLD + quad * 8]);
      bf16x8 b1 = ld8(&Ks[(j * 16 + l15) * KLD + 32 + quad * 8]);
      s[j] = MFMA(qa0, b0, s[j]);
      s[j] = MFMA(qa1, b1, s[j]);
    }

    if (more) {
      // bar1: all waves done reading Ks; own prev WRITEV drained (lgkm0).
      asm volatile("s_waitcnt lgkmcnt(0)" ::: "memory");
      __builtin_amdgcn_s_barrier();
      __builtin_amdgcn_sched_barrier(0);
      WRITEK()   // next chunk's K; ds_writes drain under softmax+PV
    }

    // exp (no max shift), causal zeroing on the last chunk only, per-lane li
    const bool lastc = (c == nch - 1);
#pragma unroll
    for (int r = 0; r < 4; r++) {
      const int swr = ((r & 1) << 3) | (quad << 1) | (r >> 1);  // sigma write row
#pragma unroll
      for (int j = 0; j < 8; j++) {
        float e = __expf(s[j][r]);
        if (lastc && (c * 128 + j * 16 + l15 > qrow_base + r)) e = 0.f;
        li[r] += e;
        ps[swr * VLD + j * 16 + l15] = f2bf(e);
      }
    }

    // PV: P(16x128) @ V(128x64); P read back in A-layout (wave-private, sigma rows)
#pragma unroll
    for (int c4 = 0; c4 < 4; c4++) {
      bf16x8 pa = ld8(&ps[srd * VLD + c4 * 32 + quad * 8]);
#pragma unroll
      for (int j2 = 0; j2 < 4; j2++) {
        bf16x8 vb = ld8(&VTs[(j2 * 16 + l15) * VLD + c4 * 32 + quad * 8]);
        o[j2] = MFMA(pa, vb, o[j2]);
      }
    }

    if (more) {
      __syncthreads();  // bar2: all waves done reading VTs; publishes WRITEK
      WRITEV()          // next chunk's V; ds_writes drain under next QK
    }
  }

  // one-time li reduction across the 16-lane column group
#pragma unroll
  for (int r = 0; r < 4; r++) {
#pragma unroll
    for (int off = 8; off >= 1; off >>= 1) li[r] += __shfl_xor(li[r], off, 16);
    li[r] = 1.0f / li[r];
  }

  // stage O in Ps (sigma rows) then coalesced u16x8 stores
#pragma unroll
  for (int j = 0; j < 4; j++)
#pragma unroll
    for (int r = 0; r < 4; r++) {
      const int swr = ((r & 1) << 3) | (quad << 1) | (r >> 1);
      ps[swr * VLD + j * 16 + l15] = f2bf(o[j][r] * li[r]);
    }
  __syncthreads();

  const int b = bh >> 4, h = bh & 15;
  {
    int sr2 = tid >> 3, sc2 = (tid & 7) * 8;
#pragma unroll
    for (int p = 0; p < 2; p++) {
      int row = sr2 + p * 32;              // logical O row 0..63
      int m = row & 15;
      int srow = ((m & 1) << 3) | ((m >> 2) << 1) | ((m >> 1) & 1);
      int t = qt * 64 + row;
      *(u16x8*)&yb[((size_t)(b * T_SEQ + t) * NH + h) * HD + sc2] =
          *(const u16x8*)&Ps[((row & 48) | srow) * VLD + sc2];
    }
  }
}

// ---------------- launch ----------------
extern "C" void kernel_launch(void* const* d_in, const int* in_sizes, int n_in,
                              void* d_out, int out_size, void* d_ws, size_t ws_size,
                              hipStream_t stream) {
  const float* x      = (const float*)d_in[0];
  // d_in[1] = mask (causal tril) — recomputed analytically, not read
  const float* rsin   = (const float*)d_in[2];
  const float* rcos   = (const float*)d_in[3];
  const float* qkv_w  = (const float*)d_in[4];
  const float* qkv_b  = (const float*)d_in[5];
  const float* proj_w = (const float*)d_in[6];
  const float* proj_b = (const float*)d_in[7];
  float* out = (float*)d_out;

  char* ws = (char*)d_ws;
  u16* x_bf  = (u16*)(ws);                    // 4096*1024      = 8 MB
  u16* qkvT  = (u16*)(ws + (8ull << 20));     // 3072*1024      = 6 MB
  u16* projT = (u16*)(ws + (14ull << 20));    // 1024*1024      = 2 MB
  u16* q_buf = (u16*)(ws + (16ull << 20));    // [b,h,t,d]      = 8 MB
  u16* k_buf = (u16*)(ws + (24ull << 20));    // [b,h,t,d]      = 8 MB
  u16* vT    = (u16*)(ws + (32ull << 20));    // [b,h,d,t]      = 8 MB
  u16* y_buf = (u16*)(ws + (40ull << 20));    // [b,t,h,d]      = 8 MB

  hipLaunchKernelGGL(k_prep, dim3(8192), dim3(256), 0, stream,
                     x, x_bf, qkv_w, qkvT, proj_w, projT);
  hipLaunchKernelGGL(k_gemm_qkv, dim3(768), dim3(256), 0, stream,
                     x_bf, qkvT, qkv_b, rsin, rcos, q_buf, k_buf, vT);
  hipLaunchKernelGGL(k_attn, dim3(32, 32), dim3(256), 0, stream,
                     q_buf, k_buf, vT, y_buf);
  hipLaunchKernelGGL(k_gemm_proj, dim3(256), dim3(256), 0, stream,
                     y_buf, projT, proj_b, out);
}